// Round 11
// baseline (427.642 us; speedup 1.0000x reference)
//
#include <hip/hip_runtime.h>
#include <hip/hip_bf16.h>
#include <hip/hip_cooperative_groups.h>

namespace cg = cooperative_groups;

// Problem constants (B=2, T=2048, C=1024, H=16, G=4, hd=64, KV=256, WINDOW=256)
#define TT 2048
#define CC 1024
#define QKVD 1536

typedef __bf16 bf16x8 __attribute__((ext_vector_type(8)));
typedef float f32x4 __attribute__((ext_vector_type(4)));

// async global->LDS, 16B per lane. LDS dest is wave-uniform base + lane*16 (HW rule).
__device__ __forceinline__ void gload_lds16(const __hip_bfloat16* g, __hip_bfloat16* l) {
  __builtin_amdgcn_global_load_lds(
      (const __attribute__((address_space(1))) unsigned int*)g,
      (__attribute__((address_space(3))) unsigned int*)l, 16, 0, 0);
}

// ===================================================================================
// Standalone kernels (R8-proven fallback path)
// ===================================================================================

__global__ __launch_bounds__(256) void k_prep(const float* __restrict__ x,
                                              const float* __restrict__ Wq,
                                              const float* __restrict__ Wk,
                                              const float* __restrict__ Wv,
                                              const float* __restrict__ Wo,
                                              const float* __restrict__ bq,
                                              const float* __restrict__ bk,
                                              const float* __restrict__ bv,
                                              __hip_bfloat16* __restrict__ xbf,
                                              __hip_bfloat16* __restrict__ wqkvT,
                                              __hip_bfloat16* __restrict__ woT,
                                              float* __restrict__ bqkv) {
  const int bxid = blockIdx.x;
  if (bxid < 4096) {
    size_t idx = ((size_t)bxid * 256 + threadIdx.x) * 4;
    float4 v = *(const float4*)(x + idx);
    xbf[idx + 0] = __float2bfloat16(v.x);
    xbf[idx + 1] = __float2bfloat16(v.y);
    xbf[idx + 2] = __float2bfloat16(v.z);
    xbf[idx + 3] = __float2bfloat16(v.w);
    return;
  }
  if (bxid == 4736) {
    for (int i = threadIdx.x; i < 1536; i += 256) {
      float v;
      if (i < 1024)      v = bq[i];
      else if (i < 1280) v = bk[i - 1024];
      else               v = bv[i - 1280];
      bqkv[i] = v;
    }
    return;
  }
  __shared__ float tile[64][65];
  const float* src;
  int ncols, k0, n0;
  __hip_bfloat16* dst;
  if (bxid < 4480) {
    const int idx = bxid - 4096;          // 384 tiles: 16 k x 24 n
    k0 = (idx & 15) * 64;
    n0 = (idx >> 4) * 64;
    dst = wqkvT;
    if (n0 < 1024)      { src = Wq; ncols = 1024; }
    else if (n0 < 1280) { src = Wk - 1024; ncols = 256; }
    else                { src = Wv - 1280; ncols = 256; }
  } else {
    const int idx = bxid - 4480;          // 256 tiles: 16 k x 16 n
    k0 = (idx & 15) * 64;
    n0 = (idx >> 4) * 64;
    dst = woT; src = Wo; ncols = 1024;
  }
  const int rw = threadIdx.x >> 6;
  const int cl = threadIdx.x & 63;
#pragma unroll
  for (int i = 0; i < 16; ++i) {
    const int kr = rw + i * 4;
    tile[kr][cl] = src[(size_t)(k0 + kr) * ncols + n0 + cl];
  }
  __syncthreads();
#pragma unroll
  for (int i = 0; i < 16; ++i) {
    const int nr = rw + i * 4;
    dst[(size_t)(n0 + nr) * 1024 + k0 + cl] = __float2bfloat16(tile[cl][nr]);
  }
}

__global__ __launch_bounds__(256, 3) void k_gemm1(const __hip_bfloat16* __restrict__ A,
                                                  const __hip_bfloat16* __restrict__ BT,
                                                  const float* __restrict__ bias,
                                                  __hip_bfloat16* __restrict__ C,
                                                  __hip_bfloat16* __restrict__ vtg) {
  __shared__ __hip_bfloat16 As[128][64];
  __shared__ __hip_bfloat16 Bs[128][64];

  const int tid  = threadIdx.x;
  const int m0   = blockIdx.y * 128;
  const int n0   = blockIdx.x * 128;
  const int w    = tid >> 6;
  const int lane = tid & 63;
  const int quad = lane >> 4;
  const int l16  = lane & 15;
  const int wm   = (w >> 1) * 64;
  const int wn   = (w & 1) * 64;

  const int dl_r = lane >> 3;
  const int dl_c = (lane & 7) ^ dl_r;

  const __hip_bfloat16* gA = A + (size_t)(m0 + w * 32 + dl_r) * 1024 + dl_c * 8;
  const __hip_bfloat16* gB = BT + (size_t)(n0 + w * 32 + dl_r) * 1024 + dl_c * 8;

  f32x4 acc[4][4] = {};

  for (int kt = 0; kt < 16; ++kt) {
    const int k0 = kt << 6;
#pragma unroll
    for (int rr = 0; rr < 4; ++rr) {
      gload_lds16(gA + k0 + (size_t)(rr * 8) * 1024, &As[w * 32 + rr * 8][0]);
      gload_lds16(gB + k0 + (size_t)(rr * 8) * 1024, &Bs[w * 32 + rr * 8][0]);
    }
    __syncthreads();

#pragma unroll
    for (int ks = 0; ks < 2; ++ks) {
      const int cb = (ks << 2) + quad;
      bf16x8 fa[4], fb[4];
#pragma unroll
      for (int i = 0; i < 4; ++i)
        fa[i] = *(const bf16x8*)&As[wm + i * 16 + l16][(cb ^ (l16 & 7)) << 3];
#pragma unroll
      for (int j = 0; j < 4; ++j)
        fb[j] = *(const bf16x8*)&Bs[wn + j * 16 + l16][(cb ^ (l16 & 7)) << 3];
#pragma unroll
      for (int i = 0; i < 4; ++i)
#pragma unroll
        for (int j = 0; j < 4; ++j)
          acc[i][j] = __builtin_amdgcn_mfma_f32_16x16x32_bf16(fa[i], fb[j], acc[i][j], 0, 0, 0);
    }
    __syncthreads();
  }

#pragma unroll
  for (int j = 0; j < 4; ++j) {
    const int gn = n0 + wn + j * 16 + l16;
    const float bias_v = bias[gn];
    if (gn >= 1280) {
      const int dfull = gn - 1280;
      const int gg = dfull >> 6;
      const int dd = dfull & 63;
#pragma unroll
      for (int i = 0; i < 4; ++i) {
        const int gm = m0 + wm + i * 16 + quad * 4;
        const int bb = gm >> 11;
        const int tl = gm & 2047;
        __hip_bfloat16 tmp[4];
#pragma unroll
        for (int r = 0; r < 4; ++r) tmp[r] = __float2bfloat16(acc[i][j][r] + bias_v);
        *(uint2*)(vtg + ((size_t)((bb * 4 + gg) * 64 + dd)) * TT + tl) = *(const uint2*)tmp;
      }
    } else {
#pragma unroll
      for (int i = 0; i < 4; ++i) {
        const int gmb = m0 + wm + i * 16 + quad * 4;
#pragma unroll
        for (int r = 0; r < 4; ++r)
          C[(size_t)(gmb + r) * QKVD + gn] = __float2bfloat16(acc[i][j][r] + bias_v);
      }
    }
  }
}

__global__ __launch_bounds__(256, 4) void k_gemm2(const __hip_bfloat16* __restrict__ A,
                                                  const __hip_bfloat16* __restrict__ BT,
                                                  const float* __restrict__ bias,
                                                  float* __restrict__ C) {
  __shared__ __hip_bfloat16 As[64][64];
  __shared__ __hip_bfloat16 Bs[128][64];

  const int tid  = threadIdx.x;
  const int m0   = blockIdx.y * 64;
  const int n0   = blockIdx.x * 128;
  const int w    = tid >> 6;
  const int lane = tid & 63;
  const int quad = lane >> 4;
  const int l16  = lane & 15;
  const int wm   = (w >> 1) * 32;
  const int wn   = (w & 1) * 64;

  const int dl_r = lane >> 3;
  const int dl_c = (lane & 7) ^ dl_r;

  const __hip_bfloat16* gA = A + (size_t)(m0 + w * 16 + dl_r) * 1024 + dl_c * 8;
  const __hip_bfloat16* gB = BT + (size_t)(n0 + w * 32 + dl_r) * 1024 + dl_c * 8;

  f32x4 acc[2][4] = {};

  for (int kt = 0; kt < 16; ++kt) {
    const int k0 = kt << 6;
    gload_lds16(gA + k0,                     &As[w * 16][0]);
    gload_lds16(gA + k0 + (size_t)8 * 1024,  &As[w * 16 + 8][0]);
    gload_lds16(gB + k0,                     &Bs[w * 32][0]);
    gload_lds16(gB + k0 + (size_t)8 * 1024,  &Bs[w * 32 + 8][0]);
    gload_lds16(gB + k0 + (size_t)16 * 1024, &Bs[w * 32 + 16][0]);
    gload_lds16(gB + k0 + (size_t)24 * 1024, &Bs[w * 32 + 24][0]);
    __syncthreads();

#pragma unroll
    for (int ks = 0; ks < 2; ++ks) {
      const int cb = (ks << 2) + quad;
      bf16x8 fa[2], fb[4];
#pragma unroll
      for (int i = 0; i < 2; ++i)
        fa[i] = *(const bf16x8*)&As[wm + i * 16 + l16][(cb ^ (l16 & 7)) << 3];
#pragma unroll
      for (int j = 0; j < 4; ++j)
        fb[j] = *(const bf16x8*)&Bs[wn + j * 16 + l16][(cb ^ (l16 & 7)) << 3];
#pragma unroll
      for (int i = 0; i < 2; ++i)
#pragma unroll
        for (int j = 0; j < 4; ++j)
          acc[i][j] = __builtin_amdgcn_mfma_f32_16x16x32_bf16(fa[i], fb[j], acc[i][j], 0, 0, 0);
    }
    __syncthreads();
  }

#pragma unroll
  for (int j = 0; j < 4; ++j) {
    const int gn = n0 + wn + j * 16 + l16;
    const float bias_v = bias[gn];
#pragma unroll
    for (int i = 0; i < 2; ++i) {
      const int gmb = m0 + wm + i * 16 + quad * 4;
#pragma unroll
      for (int r = 0; r < 4; ++r)
        C[(size_t)(gmb + r) * CC + gn] = acc[i][j][r] + bias_v;
    }
  }
}

__global__ __launch_bounds__(256) void k_attn(const __hip_bfloat16* __restrict__ qkv,
                                              const __hip_bfloat16* __restrict__ vtg,
                                              __hip_bfloat16* __restrict__ y) {
  __shared__ __hip_bfloat16 Kb[2][64][64];
  __shared__ __hip_bfloat16 Vb[2][64][64];
  __shared__ __hip_bfloat16 Ps[4][16][72];

  const int t    = threadIdx.x;
  const int w    = t >> 6;
  const int lane = t & 63;
  const int quad = lane >> 4;
  const int l16  = lane & 15;
  const int bx   = blockIdx.x;
  const int h    = blockIdx.y;
  const int b    = blockIdx.z;
  const int g    = h >> 2;
  const int i0   = bx * 64;
  const int qrow      = i0 + w * 16 + l16;
  const int my_q_base = i0 + w * 16 + quad * 4;

  const int lrow = lane >> 3;
  const int cgl  = (lane & 7) ^ lrow;

  const __hip_bfloat16* kg =
      qkv + ((size_t)(b * TT + w * 16 + lrow)) * QKVD + 1024 + g * 64 + cgl * 8;
  const __hip_bfloat16* vg =
      vtg + ((size_t)((b * 4 + g) * 64 + w * 16 + lrow)) * TT + cgl * 8;

  bf16x8 fq[2];
  {
    const __hip_bfloat16* qp = qkv + ((size_t)(b * TT + qrow)) * QKVD + h * 64 + quad * 8;
    fq[0] = *(const bf16x8*)qp;
    fq[1] = *(const bf16x8*)(qp + 32);
  }

  float l_r[4] = {0.f, 0.f, 0.f, 0.f};
  f32x4 o_acc[4] = {};
  const float EC = 0.125f * 1.44269504f;

  const int c_lo = bx >= 4 ? bx - 4 : 0;

  {
    const size_t ko = (size_t)(c_lo * 64) * QKVD;
    gload_lds16(kg + ko,                    &Kb[0][w * 16][0]);
    gload_lds16(kg + ko + (size_t)8 * QKVD, &Kb[0][w * 16 + 8][0]);
    const int vo = c_lo * 64;
    gload_lds16(vg + vo,                  &Vb[0][w * 16][0]);
    gload_lds16(vg + vo + (size_t)8 * TT, &Vb[0][w * 16 + 8][0]);
  }

  int buf = 0;
  for (int c = c_lo; c <= bx; ++c) {
    __syncthreads();
    if (c < bx) {
      const size_t ko = (size_t)((c + 1) * 64) * QKVD;
      gload_lds16(kg + ko,                    &Kb[buf ^ 1][w * 16][0]);
      gload_lds16(kg + ko + (size_t)8 * QKVD, &Kb[buf ^ 1][w * 16 + 8][0]);
      const int vo = (c + 1) * 64;
      gload_lds16(vg + vo,                  &Vb[buf ^ 1][w * 16][0]);
      gload_lds16(vg + vo + (size_t)8 * TT, &Vb[buf ^ 1][w * 16 + 8][0]);
    }

    const int jc = c * 64;

    f32x4 sacc[4] = {};
#pragma unroll
    for (int ks = 0; ks < 2; ++ks) {
      const int sw = (((ks << 2) + quad) ^ (l16 & 7)) << 3;
#pragma unroll
      for (int nt = 0; nt < 4; ++nt) {
        const bf16x8 fk = *(const bf16x8*)&Kb[buf][nt * 16 + l16][sw];
        sacc[nt] = __builtin_amdgcn_mfma_f32_16x16x32_bf16(fq[ks], fk, sacc[nt], 0, 0, 0);
      }
    }

    if (c == bx) {            // diagonal: key <= i
#pragma unroll
      for (int r = 0; r < 4; ++r) {
        const int gi = my_q_base + r;
#pragma unroll
        for (int nt = 0; nt < 4; ++nt) {
          const int key = jc + nt * 16 + l16;
          const float p = (key <= gi) ? exp2f(sacc[nt][r] * EC) : 0.f;
          l_r[r] += p;
          Ps[w][quad * 4 + r][nt * 16 + l16] = __float2bfloat16(p);
        }
      }
    } else if (bx >= 4 && c == c_lo) {  // window tail: key >= i - 256
#pragma unroll
      for (int r = 0; r < 4; ++r) {
        const int glo = my_q_base + r - 256;
#pragma unroll
        for (int nt = 0; nt < 4; ++nt) {
          const int key = jc + nt * 16 + l16;
          const float p = (key >= glo) ? exp2f(sacc[nt][r] * EC) : 0.f;
          l_r[r] += p;
          Ps[w][quad * 4 + r][nt * 16 + l16] = __float2bfloat16(p);
        }
      }
    } else {                  // interior: mask-free
#pragma unroll
      for (int r = 0; r < 4; ++r)
#pragma unroll
        for (int nt = 0; nt < 4; ++nt) {
          const float p = exp2f(sacc[nt][r] * EC);
          l_r[r] += p;
          Ps[w][quad * 4 + r][nt * 16 + l16] = __float2bfloat16(p);
        }
    }

    const bf16x8 fp0 = *(const bf16x8*)&Ps[w][l16][quad * 8];
    const bf16x8 fp1 = *(const bf16x8*)&Ps[w][l16][32 + quad * 8];

#pragma unroll
    for (int ks = 0; ks < 2; ++ks) {
      const int sw = (((ks << 2) + quad) ^ (l16 & 7)) << 3;
#pragma unroll
      for (int jt = 0; jt < 4; ++jt) {
        const bf16x8 fv = *(const bf16x8*)&Vb[buf][jt * 16 + l16][sw];
        o_acc[jt] = __builtin_amdgcn_mfma_f32_16x16x32_bf16(ks == 0 ? fp0 : fp1, fv,
                                                            o_acc[jt], 0, 0, 0);
      }
    }
    buf ^= 1;
  }

#pragma unroll
  for (int r = 0; r < 4; ++r) {
#pragma unroll
    for (int d = 1; d < 16; d <<= 1) l_r[r] += __shfl_xor(l_r[r], d);
    const float inv = 1.f / l_r[r];
    __hip_bfloat16* yp = y + ((size_t)(b * TT + my_q_base + r)) * CC + h * 64 + l16;
#pragma unroll
    for (int jt = 0; jt < 4; ++jt)
      yp[jt * 16] = __float2bfloat16(o_acc[jt][r] * inv);
  }
}

// ===================================================================================
// Fused cooperative kernel: prep -> gemm1 -> attn -> gemm2, grid-stride phases
// ===================================================================================

union SMem {
  float ptile[64][65];                                                       // 16.25 KB
  struct { __hip_bfloat16 As[128][64]; __hip_bfloat16 Bs[128][64]; } g1;     // 32 KB
  struct {
    __hip_bfloat16 Kb[2][64][64];
    __hip_bfloat16 Vb[2][64][64];
    __hip_bfloat16 Ps[4][16][72];
  } at;                                                                       // 41.2 KB
  struct { __hip_bfloat16 As[64][64]; __hip_bfloat16 Bs[128][64]; } g2;      // 24 KB
};

__global__ __launch_bounds__(256, 2) void k_fused(
    const float* __restrict__ x, const float* __restrict__ Wq, const float* __restrict__ bq,
    const float* __restrict__ Wk, const float* __restrict__ bk,
    const float* __restrict__ Wv, const float* __restrict__ bv,
    const float* __restrict__ Wo, const float* __restrict__ bo,
    float* __restrict__ out,
    __hip_bfloat16* __restrict__ xbf, __hip_bfloat16* __restrict__ qkv,
    __hip_bfloat16* __restrict__ ybf, __hip_bfloat16* __restrict__ wqkvT,
    __hip_bfloat16* __restrict__ woT, float* __restrict__ bqkv,
    __hip_bfloat16* __restrict__ vtg) {
  cg::grid_group gridg = cg::this_grid();
  __shared__ SMem sm;

  const int tid  = threadIdx.x;
  const int nblk = gridDim.x;
  const int w    = tid >> 6;
  const int lane = tid & 63;
  const int quad = lane >> 4;
  const int l16  = lane & 15;

  // ---------- phase 0: prep ----------
  for (int vb = blockIdx.x; vb < 4737; vb += nblk) {
    if (vb < 4096) {
      size_t idx = ((size_t)vb * 256 + tid) * 4;
      float4 v = *(const float4*)(x + idx);
      xbf[idx + 0] = __float2bfloat16(v.x);
      xbf[idx + 1] = __float2bfloat16(v.y);
      xbf[idx + 2] = __float2bfloat16(v.z);
      xbf[idx + 3] = __float2bfloat16(v.w);
    } else if (vb == 4736) {
      for (int i = tid; i < 1536; i += 256) {
        float v;
        if (i < 1024)      v = bq[i];
        else if (i < 1280) v = bk[i - 1024];
        else               v = bv[i - 1280];
        bqkv[i] = v;
      }
    } else {
      const float* src;
      int ncols, k0, n0;
      __hip_bfloat16* dst;
      if (vb < 4480) {
        const int idx = vb - 4096;
        k0 = (idx & 15) * 64;
        n0 = (idx >> 4) * 64;
        dst = wqkvT;
        if (n0 < 1024)      { src = Wq; ncols = 1024; }
        else if (n0 < 1280) { src = Wk - 1024; ncols = 256; }
        else                { src = Wv - 1280; ncols = 256; }
      } else {
        const int idx = vb - 4480;
        k0 = (idx & 15) * 64;
        n0 = (idx >> 4) * 64;
        dst = woT; src = Wo; ncols = 1024;
      }
      const int rw = tid >> 6;
      const int cl = tid & 63;
      __syncthreads();
#pragma unroll
      for (int i = 0; i < 16; ++i) {
        const int kr = rw + i * 4;
        sm.ptile[kr][cl] = src[(size_t)(k0 + kr) * ncols + n0 + cl];
      }
      __syncthreads();
#pragma unroll
      for (int i = 0; i < 16; ++i) {
        const int nr = rw + i * 4;
        dst[(size_t)(n0 + nr) * 1024 + k0 + cl] = __float2bfloat16(sm.ptile[cl][nr]);
      }
    }
  }
  __threadfence();
  gridg.sync();

  // ---------- phase 1: gemm1 (384 tiles of 128x128) ----------
  for (int tile = blockIdx.x; tile < 384; tile += nblk) {
    const int m0 = (tile / 12) * 128;
    const int n0 = (tile % 12) * 128;
    const int wm = (w >> 1) * 64;
    const int wn = (w & 1) * 64;
    const int dl_r = lane >> 3;
    const int dl_c = (lane & 7) ^ dl_r;

    const __hip_bfloat16* gA = xbf + (size_t)(m0 + w * 32 + dl_r) * 1024 + dl_c * 8;
    const __hip_bfloat16* gB = wqkvT + (size_t)(n0 + w * 32 + dl_r) * 1024 + dl_c * 8;

    f32x4 acc[4][4] = {};
    __syncthreads();  // LDS reuse guard across tile iterations

    for (int kt = 0; kt < 16; ++kt) {
      const int k0 = kt << 6;
#pragma unroll
      for (int rr = 0; rr < 4; ++rr) {
        gload_lds16(gA + k0 + (size_t)(rr * 8) * 1024, &sm.g1.As[w * 32 + rr * 8][0]);
        gload_lds16(gB + k0 + (size_t)(rr * 8) * 1024, &sm.g1.Bs[w * 32 + rr * 8][0]);
      }
      __syncthreads();

#pragma unroll
      for (int ks = 0; ks < 2; ++ks) {
        const int cb = (ks << 2) + quad;
        bf16x8 fa[4], fb[4];
#pragma unroll
        for (int i = 0; i < 4; ++i)
          fa[i] = *(const bf16x8*)&sm.g1.As[wm + i * 16 + l16][(cb ^ (l16 & 7)) << 3];
#pragma unroll
        for (int j = 0; j < 4; ++j)
          fb[j] = *(const bf16x8*)&sm.g1.Bs[wn + j * 16 + l16][(cb ^ (l16 & 7)) << 3];
#pragma unroll
        for (int i = 0; i < 4; ++i)
#pragma unroll
          for (int j = 0; j < 4; ++j)
            acc[i][j] = __builtin_amdgcn_mfma_f32_16x16x32_bf16(fa[i], fb[j], acc[i][j], 0, 0, 0);
      }
      __syncthreads();
    }

#pragma unroll
    for (int j = 0; j < 4; ++j) {
      const int gn = n0 + wn + j * 16 + l16;
      const float bias_v = bqkv[gn];
      if (gn >= 1280) {
        const int dfull = gn - 1280;
        const int gg = dfull >> 6;
        const int dd = dfull & 63;
#pragma unroll
        for (int i = 0; i < 4; ++i) {
          const int gm = m0 + wm + i * 16 + quad * 4;
          const int bb = gm >> 11;
          const int tl = gm & 2047;
          __hip_bfloat16 tmp[4];
#pragma unroll
          for (int r = 0; r < 4; ++r) tmp[r] = __float2bfloat16(acc[i][j][r] + bias_v);
          *(uint2*)(vtg + ((size_t)((bb * 4 + gg) * 64 + dd)) * TT + tl) = *(const uint2*)tmp;
        }
      } else {
#pragma unroll
        for (int i = 0; i < 4; ++i) {
          const int gmb = m0 + wm + i * 16 + quad * 4;
#pragma unroll
          for (int r = 0; r < 4; ++r)
            qkv[(size_t)(gmb + r) * QKVD + gn] = __float2bfloat16(acc[i][j][r] + bias_v);
        }
      }
    }
  }
  __threadfence();
  gridg.sync();

  // ---------- phase 2: attention (1024 tiles of 64 q-rows) ----------
  for (int tile = blockIdx.x; tile < 1024; tile += nblk) {
    const int bx = tile & 31;
    const int h  = (tile >> 5) & 15;
    const int b  = tile >> 9;
    const int g  = h >> 2;
    const int i0 = bx * 64;
    const int qrow      = i0 + w * 16 + l16;
    const int my_q_base = i0 + w * 16 + quad * 4;

    const int lrow = lane >> 3;
    const int cgl  = (lane & 7) ^ lrow;

    const __hip_bfloat16* kg =
        qkv + ((size_t)(b * TT + w * 16 + lrow)) * QKVD + 1024 + g * 64 + cgl * 8;
    const __hip_bfloat16* vg =
        vtg + ((size_t)((b * 4 + g) * 64 + w * 16 + lrow)) * TT + cgl * 8;

    bf16x8 fq[2];
    {
      const __hip_bfloat16* qp = qkv + ((size_t)(b * TT + qrow)) * QKVD + h * 64 + quad * 8;
      fq[0] = *(const bf16x8*)qp;
      fq[1] = *(const bf16x8*)(qp + 32);
    }

    float l_r[4] = {0.f, 0.f, 0.f, 0.f};
    f32x4 o_acc[4] = {};
    const float EC = 0.125f * 1.44269504f;

    const int c_lo = bx >= 4 ? bx - 4 : 0;

    __syncthreads();  // LDS reuse guard across tile iterations
    {
      const size_t ko = (size_t)(c_lo * 64) * QKVD;
      gload_lds16(kg + ko,                    &sm.at.Kb[0][w * 16][0]);
      gload_lds16(kg + ko + (size_t)8 * QKVD, &sm.at.Kb[0][w * 16 + 8][0]);
      const int vo = c_lo * 64;
      gload_lds16(vg + vo,                  &sm.at.Vb[0][w * 16][0]);
      gload_lds16(vg + vo + (size_t)8 * TT, &sm.at.Vb[0][w * 16 + 8][0]);
    }

    int buf = 0;
    for (int c = c_lo; c <= bx; ++c) {
      __syncthreads();
      if (c < bx) {
        const size_t ko = (size_t)((c + 1) * 64) * QKVD;
        gload_lds16(kg + ko,                    &sm.at.Kb[buf ^ 1][w * 16][0]);
        gload_lds16(kg + ko + (size_t)8 * QKVD, &sm.at.Kb[buf ^ 1][w * 16 + 8][0]);
        const int vo = (c + 1) * 64;
        gload_lds16(vg + vo,                  &sm.at.Vb[buf ^ 1][w * 16][0]);
        gload_lds16(vg + vo + (size_t)8 * TT, &sm.at.Vb[buf ^ 1][w * 16 + 8][0]);
      }

      const int jc = c * 64;

      f32x4 sacc[4] = {};
#pragma unroll
      for (int ks = 0; ks < 2; ++ks) {
        const int sw = (((ks << 2) + quad) ^ (l16 & 7)) << 3;
#pragma unroll
        for (int nt = 0; nt < 4; ++nt) {
          const bf16x8 fk = *(const bf16x8*)&sm.at.Kb[buf][nt * 16 + l16][sw];
          sacc[nt] = __builtin_amdgcn_mfma_f32_16x16x32_bf16(fq[ks], fk, sacc[nt], 0, 0, 0);
        }
      }

      if (c == bx) {
#pragma unroll
        for (int r = 0; r < 4; ++r) {
          const int gi = my_q_base + r;
#pragma unroll
          for (int nt = 0; nt < 4; ++nt) {
            const int key = jc + nt * 16 + l16;
            const float p = (key <= gi) ? exp2f(sacc[nt][r] * EC) : 0.f;
            l_r[r] += p;
            sm.at.Ps[w][quad * 4 + r][nt * 16 + l16] = __float2bfloat16(p);
          }
        }
      } else if (bx >= 4 && c == c_lo) {
#pragma unroll
        for (int r = 0; r < 4; ++r) {
          const int glo = my_q_base + r - 256;
#pragma unroll
          for (int nt = 0; nt < 4; ++nt) {
            const int key = jc + nt * 16 + l16;
            const float p = (key >= glo) ? exp2f(sacc[nt][r] * EC) : 0.f;
            l_r[r] += p;
            sm.at.Ps[w][quad * 4 + r][nt * 16 + l16] = __float2bfloat16(p);
          }
        }
      } else {
#pragma unroll
        for (int r = 0; r < 4; ++r)
#pragma unroll
          for (int nt = 0; nt < 4; ++nt) {
            const float p = exp2f(sacc[nt][r] * EC);
            l_r[r] += p;
            sm.at.Ps[w][quad * 4 + r][nt * 16 + l16] = __float2bfloat16(p);
          }
      }

      const bf16x8 fp0 = *(const bf16x8*)&sm.at.Ps[w][l16][quad * 8];
      const bf16x8 fp1 = *(const bf16x8*)&sm.at.Ps[w][l16][32 + quad * 8];

#pragma unroll
      for (int ks = 0; ks < 2; ++ks) {
        const int sw = (((ks << 2) + quad) ^ (l16 & 7)) << 3;
#pragma unroll
        for (int jt = 0; jt < 4; ++jt) {
          const bf16x8 fv = *(const bf16x8*)&sm.at.Vb[buf][jt * 16 + l16][sw];
          o_acc[jt] = __builtin_amdgcn_mfma_f32_16x16x32_bf16(ks == 0 ? fp0 : fp1, fv,
                                                              o_acc[jt], 0, 0, 0);
        }
      }
      buf ^= 1;
    }

#pragma unroll
    for (int r = 0; r < 4; ++r) {
#pragma unroll
      for (int d = 1; d < 16; d <<= 1) l_r[r] += __shfl_xor(l_r[r], d);
      const float inv = 1.f / l_r[r];
      __hip_bfloat16* yp = ybf + ((size_t)(b * TT + my_q_base + r)) * CC + h * 64 + l16;
#pragma unroll
      for (int jt = 0; jt < 4; ++jt)
        yp[jt * 16] = __float2bfloat16(o_acc[jt][r] * inv);
    }
  }
  __threadfence();
  gridg.sync();

  // ---------- phase 3: gemm2 (512 tiles of 64x128) ----------
  for (int tile = blockIdx.x; tile < 512; tile += nblk) {
    const int m0 = (tile >> 3) * 64;
    const int n0 = (tile & 7) * 128;
    const int wm = (w >> 1) * 32;
    const int wn = (w & 1) * 64;
    const int dl_r = lane >> 3;
    const int dl_c = (lane & 7) ^ dl_r;

    const __hip_bfloat16* gA = ybf + (size_t)(m0 + w * 16 + dl_r) * 1024 + dl_c * 8;
    const __hip_bfloat16* gB = woT + (size_t)(n0 + w * 32 + dl_r) * 1024 + dl_c * 8;

    f32x4 acc[2][4] = {};
    __syncthreads();  // LDS reuse guard

    for (int kt = 0; kt < 16; ++kt) {
      const int k0 = kt << 6;
      gload_lds16(gA + k0,                     &sm.g2.As[w * 16][0]);
      gload_lds16(gA + k0 + (size_t)8 * 1024,  &sm.g2.As[w * 16 + 8][0]);
      gload_lds16(gB + k0,                     &sm.g2.Bs[w * 32][0]);
      gload_lds16(gB + k0 + (size_t)8 * 1024,  &sm.g2.Bs[w * 32 + 8][0]);
      gload_lds16(gB + k0 + (size_t)16 * 1024, &sm.g2.Bs[w * 32 + 16][0]);
      gload_lds16(gB + k0 + (size_t)24 * 1024, &sm.g2.Bs[w * 32 + 24][0]);
      __syncthreads();

#pragma unroll
      for (int ks = 0; ks < 2; ++ks) {
        const int cb = (ks << 2) + quad;
        bf16x8 fa[2], fb[4];
#pragma unroll
        for (int i = 0; i < 2; ++i)
          fa[i] = *(const bf16x8*)&sm.g2.As[wm + i * 16 + l16][(cb ^ (l16 & 7)) << 3];
#pragma unroll
        for (int j = 0; j < 4; ++j)
          fb[j] = *(const bf16x8*)&sm.g2.Bs[wn + j * 16 + l16][(cb ^ (l16 & 7)) << 3];
#pragma unroll
        for (int i = 0; i < 2; ++i)
#pragma unroll
          for (int j = 0; j < 4; ++j)
            acc[i][j] = __builtin_amdgcn_mfma_f32_16x16x32_bf16(fa[i], fb[j], acc[i][j], 0, 0, 0);
      }
      __syncthreads();
    }

#pragma unroll
    for (int j = 0; j < 4; ++j) {
      const int gn = n0 + wn + j * 16 + l16;
      const float bias_v = bo[gn];
#pragma unroll
      for (int i = 0; i < 2; ++i) {
        const int gmb = m0 + wm + i * 16 + quad * 4;
#pragma unroll
        for (int r = 0; r < 4; ++r)
          out[(size_t)(gmb + r) * CC + gn] = acc[i][j][r] + bias_v;
      }
    }
  }
}

// ---------------- launch ----------------

extern "C" void kernel_launch(void* const* d_in, const int* in_sizes, int n_in,
                              void* d_out, int out_size, void* d_ws, size_t ws_size,
                              hipStream_t stream) {
  const float* x  = (const float*)d_in[0];
  const float* Wq = (const float*)d_in[1];
  const float* bq = (const float*)d_in[2];
  const float* Wk = (const float*)d_in[3];
  const float* bk = (const float*)d_in[4];
  const float* Wv = (const float*)d_in[5];
  const float* bv = (const float*)d_in[6];
  const float* Wo = (const float*)d_in[7];
  const float* bo = (const float*)d_in[8];
  float* out = (float*)d_out;

  char* ws = (char*)d_ws;
  const size_t M = 2 * TT;  // 4096
  __hip_bfloat16* xbf   = (__hip_bfloat16*)(ws);               // 8 MB
  __hip_bfloat16* qkv   = (__hip_bfloat16*)(ws + 8388608);     // 12 MB (V region unused)
  __hip_bfloat16* ybf   = (__hip_bfloat16*)(ws + 20971520);    // 8 MB
  __hip_bfloat16* wqkvT = (__hip_bfloat16*)(ws + 29360128);    // 3 MB
  __hip_bfloat16* woT   = (__hip_bfloat16*)(ws + 32505856);    // 2 MB
  float*          bqkv  = (float*)(ws + 34603008);             // 6 KB
  __hip_bfloat16* vtg   = (__hip_bfloat16*)(ws + 34609152);    // 2 MB

  // capture-safe queries: cooperative support + actual co-residency capacity
  int dev = 0;
  (void)hipGetDevice(&dev);
  int coop = 0;
  (void)hipDeviceGetAttribute(&coop, hipDeviceAttributeCooperativeLaunch, dev);
  int numCU = 0;
  (void)hipDeviceGetAttribute(&numCU, hipDeviceAttributeMultiprocessorCount, dev);
  int nb = 0;
  (void)hipOccupancyMaxActiveBlocksPerMultiprocessor(&nb, k_fused, 256, 0);
  const long cap = (long)nb * (long)numCU;

  bool done = false;
  if (coop && cap >= 128) {
    int grid = (int)(cap < 512 ? cap : 512);
    void* args[] = {(void*)&x,  (void*)&Wq, (void*)&bq, (void*)&Wk, (void*)&bk,
                    (void*)&Wv, (void*)&bv, (void*)&Wo, (void*)&bo, (void*)&out,
                    (void*)&xbf, (void*)&qkv, (void*)&ybf, (void*)&wqkvT,
                    (void*)&woT, (void*)&bqkv, (void*)&vtg};
    hipError_t err = hipLaunchCooperativeKernel((const void*)k_fused, dim3(grid),
                                                dim3(256), args, 0, stream);
    if (err == hipSuccess) done = true;
    else (void)hipGetLastError();  // clear sticky error, fall through
  }

  if (!done) {
    // R8-proven 4-kernel fallback
    k_prep<<<4737, 256, 0, stream>>>(x, Wq, Wk, Wv, Wo, bq, bk, bv,
                                     xbf, wqkvT, woT, bqkv);
    k_gemm1<<<dim3(QKVD / 128, M / 128), 256, 0, stream>>>(xbf, wqkvT, bqkv, qkv, vtg);
    k_attn<<<dim3(TT / 64, 16, 2), 256, 0, stream>>>(qkv, vtg, ybf);
    k_gemm2<<<dim3(CC / 128, M / 64), 256, 0, stream>>>(ybf, woT, bo, out);
  }
}

// Round 12
// 145.429 us; speedup vs baseline: 2.9406x; 2.9406x over previous
//
#include <hip/hip_runtime.h>
#include <hip/hip_bf16.h>

// Problem constants (B=2, T=2048, C=1024, H=16, G=4, hd=64, KV=256, WINDOW=256)
#define TT 2048
#define CC 1024
#define QKVD 1536

typedef __bf16 bf16x8 __attribute__((ext_vector_type(8)));
typedef float f32x4 __attribute__((ext_vector_type(4)));

// async global->LDS, 16B per lane. LDS dest is wave-uniform base + lane*16 (HW rule).
__device__ __forceinline__ void gload_lds16(const __hip_bfloat16* g, __hip_bfloat16* l) {
  __builtin_amdgcn_global_load_lds(
      (const __attribute__((address_space(1))) unsigned int*)g,
      (__attribute__((address_space(3))) unsigned int*)l, 16, 0, 0);
}

// ---------------- merged prep: x->bf16 convert + weight packs + bias ----------------
// 1D grid: [0,4096) convert x; [4096,4480) pack wqkvT; [4480,4736) pack woT; [4736] bias.

__global__ __launch_bounds__(256) void k_prep(const float* __restrict__ x,
                                              const float* __restrict__ Wq,
                                              const float* __restrict__ Wk,
                                              const float* __restrict__ Wv,
                                              const float* __restrict__ Wo,
                                              const float* __restrict__ bq,
                                              const float* __restrict__ bk,
                                              const float* __restrict__ bv,
                                              __hip_bfloat16* __restrict__ xbf,
                                              __hip_bfloat16* __restrict__ wqkvT,
                                              __hip_bfloat16* __restrict__ woT,
                                              float* __restrict__ bqkv) {
  const int bxid = blockIdx.x;
  if (bxid < 4096) {
    size_t idx = ((size_t)bxid * 256 + threadIdx.x) * 4;
    float4 v = *(const float4*)(x + idx);
    xbf[idx + 0] = __float2bfloat16(v.x);
    xbf[idx + 1] = __float2bfloat16(v.y);
    xbf[idx + 2] = __float2bfloat16(v.z);
    xbf[idx + 3] = __float2bfloat16(v.w);
    return;
  }
  if (bxid == 4736) {
    for (int i = threadIdx.x; i < 1536; i += 256) {
      float v;
      if (i < 1024)      v = bq[i];
      else if (i < 1280) v = bk[i - 1024];
      else               v = bv[i - 1280];
      bqkv[i] = v;
    }
    return;
  }
  // weight pack via LDS tile transpose, coalesced both sides
  __shared__ float tile[64][65];
  const float* src;
  int ncols, k0, n0;
  __hip_bfloat16* dst;
  if (bxid < 4480) {
    const int idx = bxid - 4096;          // 384 tiles: 16 k x 24 n
    k0 = (idx & 15) * 64;
    n0 = (idx >> 4) * 64;
    dst = wqkvT;
    if (n0 < 1024)      { src = Wq; ncols = 1024; }
    else if (n0 < 1280) { src = Wk - 1024; ncols = 256; }
    else                { src = Wv - 1280; ncols = 256; }
  } else {
    const int idx = bxid - 4480;          // 256 tiles: 16 k x 16 n
    k0 = (idx & 15) * 64;
    n0 = (idx >> 4) * 64;
    dst = woT; src = Wo; ncols = 1024;
  }
  const int rw = threadIdx.x >> 6;
  const int cl = threadIdx.x & 63;
#pragma unroll
  for (int i = 0; i < 16; ++i) {
    const int kr = rw + i * 4;
    tile[kr][cl] = src[(size_t)(k0 + kr) * ncols + n0 + cl];
  }
  __syncthreads();
#pragma unroll
  for (int i = 0; i < 16; ++i) {
    const int nr = rw + i * 4;
    dst[(size_t)(n0 + nr) * 1024 + k0 + cl] = __float2bfloat16(tile[cl][nr]);
  }
}

// ---------------- gemm1: QKV projection, 128x128 tile, BK=64 -------------
// [4096 x 1024] * [1024 x 1536]^T-packed. Single-buffer 2-barrier K-loop, 128
// MFMA per block-barrier, XOR-swizzled conflict-free LDS.
// V columns (n>=1280) written transposed into vtg[(b*4+g)*64 + d][t]. grid (12, 32).

__global__ __launch_bounds__(256, 3) void k_gemm1(const __hip_bfloat16* __restrict__ A,
                                                  const __hip_bfloat16* __restrict__ BT,
                                                  const float* __restrict__ bias,
                                                  __hip_bfloat16* __restrict__ C,
                                                  __hip_bfloat16* __restrict__ vtg) {
  __shared__ __hip_bfloat16 As[128][64];   // 16 KB
  __shared__ __hip_bfloat16 Bs[128][64];   // 16 KB

  const int tid  = threadIdx.x;
  const int m0   = blockIdx.y * 128;
  const int n0   = blockIdx.x * 128;
  const int w    = tid >> 6;
  const int lane = tid & 63;
  const int quad = lane >> 4;
  const int l16  = lane & 15;
  const int wm   = (w >> 1) * 64;
  const int wn   = (w & 1) * 64;

  const int dl_r = lane >> 3;               // 0..7
  const int dl_c = (lane & 7) ^ dl_r;       // swizzled global 16B chunk

  const __hip_bfloat16* gA = A + (size_t)(m0 + w * 32 + dl_r) * 1024 + dl_c * 8;
  const __hip_bfloat16* gB = BT + (size_t)(n0 + w * 32 + dl_r) * 1024 + dl_c * 8;

  f32x4 acc[4][4] = {};

  for (int kt = 0; kt < 16; ++kt) {
    const int k0 = kt << 6;
#pragma unroll
    for (int rr = 0; rr < 4; ++rr) {
      gload_lds16(gA + k0 + (size_t)(rr * 8) * 1024, &As[w * 32 + rr * 8][0]);
      gload_lds16(gB + k0 + (size_t)(rr * 8) * 1024, &Bs[w * 32 + rr * 8][0]);
    }
    __syncthreads();  // drain DMA

#pragma unroll
    for (int ks = 0; ks < 2; ++ks) {
      const int cb = (ks << 2) + quad;
      bf16x8 fa[4], fb[4];
#pragma unroll
      for (int i = 0; i < 4; ++i)
        fa[i] = *(const bf16x8*)&As[wm + i * 16 + l16][(cb ^ (l16 & 7)) << 3];
#pragma unroll
      for (int j = 0; j < 4; ++j)
        fb[j] = *(const bf16x8*)&Bs[wn + j * 16 + l16][(cb ^ (l16 & 7)) << 3];
#pragma unroll
      for (int i = 0; i < 4; ++i)
#pragma unroll
        for (int j = 0; j < 4; ++j)
          acc[i][j] = __builtin_amdgcn_mfma_f32_16x16x32_bf16(fa[i], fb[j], acc[i][j], 0, 0, 0);
    }
    __syncthreads();  // all reads done before next overwrite
  }

  // epilogue: C/D layout col=lane&15, row=quad*4+reg. 1280 boundary wave-uniform per j.
#pragma unroll
  for (int j = 0; j < 4; ++j) {
    const int gn = n0 + wn + j * 16 + l16;
    const float bias_v = bias[gn];
    if (gn >= 1280) {
      // V column: write transposed into vtg[(b*4+g)*64 + d][t]
      const int dfull = gn - 1280;
      const int gg = dfull >> 6;
      const int dd = dfull & 63;
#pragma unroll
      for (int i = 0; i < 4; ++i) {
        const int gm = m0 + wm + i * 16 + quad * 4;  // 4 consecutive tokens
        const int bb = gm >> 11;
        const int tl = gm & 2047;
        __hip_bfloat16 tmp[4];
#pragma unroll
        for (int r = 0; r < 4; ++r) tmp[r] = __float2bfloat16(acc[i][j][r] + bias_v);
        *(uint2*)(vtg + ((size_t)((bb * 4 + gg) * 64 + dd)) * TT + tl) = *(const uint2*)tmp;
      }
    } else {
#pragma unroll
      for (int i = 0; i < 4; ++i) {
        const int gmb = m0 + wm + i * 16 + quad * 4;
#pragma unroll
        for (int r = 0; r < 4; ++r)
          C[(size_t)(gmb + r) * QKVD + gn] = __float2bfloat16(acc[i][j][r] + bias_v);
      }
    }
  }
}

// ---------------- gemm2: output projection, 64x128 tile, BK=64, single-buffer ------
// [4096 x 1024] * [1024 x 1024]^T-packed -> fp32 out. grid (8, 64) = 512 blocks.

__global__ __launch_bounds__(256, 4) void k_gemm2(const __hip_bfloat16* __restrict__ A,
                                                  const __hip_bfloat16* __restrict__ BT,
                                                  const float* __restrict__ bias,
                                                  float* __restrict__ C) {
  __shared__ __hip_bfloat16 As[64][64];
  __shared__ __hip_bfloat16 Bs[128][64];

  const int tid  = threadIdx.x;
  const int m0   = blockIdx.y * 64;
  const int n0   = blockIdx.x * 128;
  const int w    = tid >> 6;
  const int lane = tid & 63;
  const int quad = lane >> 4;
  const int l16  = lane & 15;
  const int wm   = (w >> 1) * 32;
  const int wn   = (w & 1) * 64;

  const int dl_r = lane >> 3;
  const int dl_c = (lane & 7) ^ dl_r;

  const __hip_bfloat16* gA = A + (size_t)(m0 + w * 16 + dl_r) * 1024 + dl_c * 8;
  const __hip_bfloat16* gB = BT + (size_t)(n0 + w * 32 + dl_r) * 1024 + dl_c * 8;

  f32x4 acc[2][4] = {};

  for (int kt = 0; kt < 16; ++kt) {
    const int k0 = kt << 6;
    gload_lds16(gA + k0,                     &As[w * 16][0]);
    gload_lds16(gA + k0 + (size_t)8 * 1024,  &As[w * 16 + 8][0]);
    gload_lds16(gB + k0,                     &Bs[w * 32][0]);
    gload_lds16(gB + k0 + (size_t)8 * 1024,  &Bs[w * 32 + 8][0]);
    gload_lds16(gB + k0 + (size_t)16 * 1024, &Bs[w * 32 + 16][0]);
    gload_lds16(gB + k0 + (size_t)24 * 1024, &Bs[w * 32 + 24][0]);
    __syncthreads();

#pragma unroll
    for (int ks = 0; ks < 2; ++ks) {
      const int cb = (ks << 2) + quad;
      bf16x8 fa[2], fb[4];
#pragma unroll
      for (int i = 0; i < 2; ++i)
        fa[i] = *(const bf16x8*)&As[wm + i * 16 + l16][(cb ^ (l16 & 7)) << 3];
#pragma unroll
      for (int j = 0; j < 4; ++j)
        fb[j] = *(const bf16x8*)&Bs[wn + j * 16 + l16][(cb ^ (l16 & 7)) << 3];
#pragma unroll
      for (int i = 0; i < 2; ++i)
#pragma unroll
        for (int j = 0; j < 4; ++j)
          acc[i][j] = __builtin_amdgcn_mfma_f32_16x16x32_bf16(fa[i], fb[j], acc[i][j], 0, 0, 0);
    }
    __syncthreads();
  }

#pragma unroll
  for (int j = 0; j < 4; ++j) {
    const int gn = n0 + wn + j * 16 + l16;
    const float bias_v = bias[gn];
#pragma unroll
    for (int i = 0; i < 2; ++i) {
      const int gmb = m0 + wm + i * 16 + quad * 4;
#pragma unroll
      for (int r = 0; r < 4; ++r)
        C[(size_t)(gmb + r) * CC + gn] = acc[i][j][r] + bias_v;
    }
  }
}

// ---------------- MFMA flash attention: LDS-staged, double-buffered ----------------
// Fixed-shift softmax + mask specialization: only diagonal chunk (c==bx) needs
// key<=i; only tail chunk (c==bx-4) needs key>=i-256; middle chunks are mask-free.

__global__ __launch_bounds__(256) void k_attn(const __hip_bfloat16* __restrict__ qkv,
                                              const __hip_bfloat16* __restrict__ vtg,
                                              __hip_bfloat16* __restrict__ y) {
  __shared__ __hip_bfloat16 Kb[2][64][64];  // [buf][key][d]   16 KB
  __shared__ __hip_bfloat16 Vb[2][64][64];  // [buf][d][key]   16 KB
  __shared__ __hip_bfloat16 Ps[4][16][72];  // per-wave P tile 9.2 KB

  const int t    = threadIdx.x;
  const int w    = t >> 6;
  const int lane = t & 63;
  const int quad = lane >> 4;
  const int l16  = lane & 15;
  const int bx   = blockIdx.x;
  const int h    = blockIdx.y;
  const int b    = blockIdx.z;
  const int g    = h >> 2;  // repeat_interleave: heads 4g..4g+3 -> group g
  const int i0   = bx * 64;
  const int qrow      = i0 + w * 16 + l16;
  const int my_q_base = i0 + w * 16 + quad * 4;

  const int lrow = lane >> 3;
  const int cgl  = (lane & 7) ^ lrow;

  const __hip_bfloat16* kg =
      qkv + ((size_t)(b * TT + w * 16 + lrow)) * QKVD + 1024 + g * 64 + cgl * 8;
  const __hip_bfloat16* vg =
      vtg + ((size_t)((b * 4 + g) * 64 + w * 16 + lrow)) * TT + cgl * 8;

  bf16x8 fq[2];
  {
    const __hip_bfloat16* qp = qkv + ((size_t)(b * TT + qrow)) * QKVD + h * 64 + quad * 8;
    fq[0] = *(const bf16x8*)qp;
    fq[1] = *(const bf16x8*)(qp + 32);
  }

  float l_r[4] = {0.f, 0.f, 0.f, 0.f};
  f32x4 o_acc[4] = {};
  const float EC = 0.125f * 1.44269504f;  // (1/sqrt(64)) * log2(e)

  const int c_lo = bx >= 4 ? bx - 4 : 0;

  {
    const size_t ko = (size_t)(c_lo * 64) * QKVD;
    gload_lds16(kg + ko,                    &Kb[0][w * 16][0]);
    gload_lds16(kg + ko + (size_t)8 * QKVD, &Kb[0][w * 16 + 8][0]);
    const int vo = c_lo * 64;
    gload_lds16(vg + vo,                  &Vb[0][w * 16][0]);
    gload_lds16(vg + vo + (size_t)8 * TT, &Vb[0][w * 16 + 8][0]);
  }

  int buf = 0;
  for (int c = c_lo; c <= bx; ++c) {
    __syncthreads();
    if (c < bx) {
      const size_t ko = (size_t)((c + 1) * 64) * QKVD;
      gload_lds16(kg + ko,                    &Kb[buf ^ 1][w * 16][0]);
      gload_lds16(kg + ko + (size_t)8 * QKVD, &Kb[buf ^ 1][w * 16 + 8][0]);
      const int vo = (c + 1) * 64;
      gload_lds16(vg + vo,                  &Vb[buf ^ 1][w * 16][0]);
      gload_lds16(vg + vo + (size_t)8 * TT, &Vb[buf ^ 1][w * 16 + 8][0]);
    }

    const int jc = c * 64;

    f32x4 sacc[4] = {};
#pragma unroll
    for (int ks = 0; ks < 2; ++ks) {
      const int sw = (((ks << 2) + quad) ^ (l16 & 7)) << 3;
#pragma unroll
      for (int nt = 0; nt < 4; ++nt) {
        const bf16x8 fk = *(const bf16x8*)&Kb[buf][nt * 16 + l16][sw];
        sacc[nt] = __builtin_amdgcn_mfma_f32_16x16x32_bf16(fq[ks], fk, sacc[nt], 0, 0, 0);
      }
    }

    // p = exp(s/8); mask only where needed (wave-uniform chunk classification)
    if (c == bx) {            // diagonal: key <= i
#pragma unroll
      for (int r = 0; r < 4; ++r) {
        const int gi = my_q_base + r;
#pragma unroll
        for (int nt = 0; nt < 4; ++nt) {
          const int key = jc + nt * 16 + l16;
          const float p = (key <= gi) ? exp2f(sacc[nt][r] * EC) : 0.f;
          l_r[r] += p;
          Ps[w][quad * 4 + r][nt * 16 + l16] = __float2bfloat16(p);
        }
      }
    } else if (bx >= 4 && c == c_lo) {  // window tail: key >= i - 256
#pragma unroll
      for (int r = 0; r < 4; ++r) {
        const int glo = my_q_base + r - 256;
#pragma unroll
        for (int nt = 0; nt < 4; ++nt) {
          const int key = jc + nt * 16 + l16;
          const float p = (key >= glo) ? exp2f(sacc[nt][r] * EC) : 0.f;
          l_r[r] += p;
          Ps[w][quad * 4 + r][nt * 16 + l16] = __float2bfloat16(p);
        }
      }
    } else {                  // interior: mask-free
#pragma unroll
      for (int r = 0; r < 4; ++r)
#pragma unroll
        for (int nt = 0; nt < 4; ++nt) {
          const float p = exp2f(sacc[nt][r] * EC);
          l_r[r] += p;
          Ps[w][quad * 4 + r][nt * 16 + l16] = __float2bfloat16(p);
        }
    }

    const bf16x8 fp0 = *(const bf16x8*)&Ps[w][l16][quad * 8];
    const bf16x8 fp1 = *(const bf16x8*)&Ps[w][l16][32 + quad * 8];

#pragma unroll
    for (int ks = 0; ks < 2; ++ks) {
      const int sw = (((ks << 2) + quad) ^ (l16 & 7)) << 3;
#pragma unroll
      for (int jt = 0; jt < 4; ++jt) {
        const bf16x8 fv = *(const bf16x8*)&Vb[buf][jt * 16 + l16][sw];
        o_acc[jt] = __builtin_amdgcn_mfma_f32_16x16x32_bf16(ks == 0 ? fp0 : fp1, fv,
                                                            o_acc[jt], 0, 0, 0);
      }
    }
    buf ^= 1;
  }

#pragma unroll
  for (int r = 0; r < 4; ++r) {
#pragma unroll
    for (int d = 1; d < 16; d <<= 1) l_r[r] += __shfl_xor(l_r[r], d);
    const float inv = 1.f / l_r[r];
    __hip_bfloat16* yp = y + ((size_t)(b * TT + my_q_base + r)) * CC + h * 64 + l16;
#pragma unroll
    for (int jt = 0; jt < 4; ++jt)
      yp[jt * 16] = __float2bfloat16(o_acc[jt][r] * inv);
  }
}

// ---------------- launch ----------------

extern "C" void kernel_launch(void* const* d_in, const int* in_sizes, int n_in,
                              void* d_out, int out_size, void* d_ws, size_t ws_size,
                              hipStream_t stream) {
  const float* x  = (const float*)d_in[0];
  const float* Wq = (const float*)d_in[1];
  const float* bq = (const float*)d_in[2];
  const float* Wk = (const float*)d_in[3];
  const float* bk = (const float*)d_in[4];
  const float* Wv = (const float*)d_in[5];
  const float* bv = (const float*)d_in[6];
  const float* Wo = (const float*)d_in[7];
  const float* bo = (const float*)d_in[8];
  float* out = (float*)d_out;

  char* ws = (char*)d_ws;
  const size_t M = 2 * TT;  // 4096
  __hip_bfloat16* xbf   = (__hip_bfloat16*)(ws);               // 8 MB
  __hip_bfloat16* qkv   = (__hip_bfloat16*)(ws + 8388608);     // 12 MB (V region unused)
  __hip_bfloat16* ybf   = (__hip_bfloat16*)(ws + 20971520);    // 8 MB
  __hip_bfloat16* wqkvT = (__hip_bfloat16*)(ws + 29360128);    // 3 MB
  __hip_bfloat16* woT   = (__hip_bfloat16*)(ws + 32505856);    // 2 MB
  float*          bqkv  = (float*)(ws + 34603008);             // 6 KB
  __hip_bfloat16* vtg   = (__hip_bfloat16*)(ws + 34609152);    // 2 MB

  // prep: x convert (4096) + wqkv pack (384) + wo pack (256) + bias (1)
  k_prep<<<4737, 256, 0, stream>>>(x, Wq, Wk, Wv, Wo, bq, bk, bv,
                                   xbf, wqkvT, woT, bqkv);

  // QKV projection: 128x128 tiles, grid (12, 32); V columns go transposed to vtg
  k_gemm1<<<dim3(QKVD / 128, M / 128), 256, 0, stream>>>(xbf, wqkvT, bqkv, qkv, vtg);

  // attention: 1024 blocks, LDS-staged double-buffered flash
  k_attn<<<dim3(TT / 64, 16, 2), 256, 0, stream>>>(qkv, vtg, ybf);

  // output projection: 64x128 tiles, grid (8, 64) -> fp32
  k_gemm2<<<dim3(CC / 128, M / 64), 256, 0, stream>>>(ybf, woT, bo, out);
}